// Round 8
// baseline (9929.738 us; speedup 1.0000x reference)
//
#include <hip/hip_runtime.h>
#include <hip/hip_fp16.h>
#include <math.h>

#define F 8
#define T_IN 336
#define T_OUT 96
#define D_OUT 2
#define NGRP 8       // batch groups (32 rows each)
#define WPG 32       // workgroups per group (unit slices)
#define ROWS 32      // batch rows per group
#define NT 512
#define HROW 2048    // LDS hcat row stride bytes

// weight regions (shorts), kb-major tiled: [(s*4+w)][kb][lane(64)][8]
#define WE0 0
#define WE1 1048576
#define WD0 3145728
#define WD1 4194304
#define W_TOTAL 6291456
#define HO0 0
#define HO1 262144
#define HBUF 131072

using f32x4 = __attribute__((ext_vector_type(4))) float;
using f16x8 = __attribute__((ext_vector_type(8))) _Float16;

struct Args {
  const float *src;
  const float *eWih0, *eb0, *eb1;
  const float *dWih0, *db0, *db1;
  const float *fcW, *fcb, *pW, *pb;
  const unsigned short *W;
  unsigned short *Hst;
  float *out;
  unsigned *cnt;
};

__device__ __forceinline__ float sigm(float x) { return 1.f / (1.f + __expf(-x)); }
__device__ __forceinline__ float tanh_f(float x) {
  float e = __expf(-2.f * fabsf(x));
  float r = (1.f - e) / (1.f + e);
  return copysignf(r, x);
}
__device__ __forceinline__ f32x4 mfma16(f16x8 a, f16x8 b, f32x4 c) {
  return __builtin_amdgcn_mfma_f32_16x16x32_f16(a, b, c, 0, 0, 0);
}
__device__ __forceinline__ void ld16_cg(uint4& d, const void* p) {
  asm volatile("global_load_dwordx4 %0, %1, off sc0 sc1" : "=v"(d) : "v"(p));
}
__device__ __forceinline__ void st2_cg(void* p, unsigned v) {
  asm volatile("global_store_short %0, %1, off sc0 sc1" :: "v"(p), "v"(v) : "memory");
}

// per-WAVE barrier: each wave drains its own sc-stores, bumps, spins.
// Group target = 32 WGs * 8 waves = 256 bumps per stage.
__device__ __forceinline__ void gbarw(unsigned* cnt, unsigned& bar, int lane) {
  bar += 256;
  asm volatile("s_waitcnt vmcnt(0)" ::: "memory");
  if (lane == 0) {
    __hip_atomic_fetch_add(cnt, 1u, __ATOMIC_RELAXED, __HIP_MEMORY_SCOPE_AGENT);
    long guard = 0;
    while (__hip_atomic_load(cnt, __ATOMIC_RELAXED, __HIP_MEMORY_SCOPE_AGENT) < bar) {
      __builtin_amdgcn_s_sleep(2);
      if (++guard > (1L << 22)) break;
    }
  }
  asm volatile("" ::: "memory");
}

// fp32 -> fp16, kb-major wave-fragment layout (identical to round 7)
__global__ __launch_bounds__(256) void conv_kernel(
    const float* eWhh0, const float* eWih1, const float* eWhh1,
    const float* dWhh0, const float* dWih1, const float* dWhh1,
    unsigned short* W) {
  size_t i = (size_t)blockIdx.x * 256 + threadIdx.x;
  if (i >= W_TOTAL) return;
  int set, j;
  if (i < WE1)      { set = 0; j = (int)i; }
  else if (i < WD0) { set = 1; j = (int)(i - WE1); }
  else if (i < WD1) { set = 2; j = (int)(i - WD0); }
  else              { set = 3; j = (int)(i - WD1); }
  const int big = (set == 1 || set == 3);
  const int e = j & 7, lane = (j >> 3) & 63, r = j >> 9;
  const int kb = big ? (r & 31) : (r & 15);
  const int sw = big ? (r >> 5) : (r >> 4);
  const int s = sw >> 2, w = sw & 3;
  const int c = lane & 15;
  const int n = (c & 3) * 512 + 16 * s + 4 * w + (c >> 2);
  const int k = kb * 32 + (lane >> 4) * 8 + e;
  float v;
  if (set == 0)      v = eWhh0[(size_t)n * 512 + k];
  else if (set == 1) v = (k < 512) ? eWih1[(size_t)n * 512 + k] : eWhh1[(size_t)n * 512 + k - 512];
  else if (set == 2) v = dWhh0[(size_t)n * 512 + k];
  else               v = (k < 512) ? dWih1[(size_t)n * 512 + k] : dWhh1[(size_t)n * 512 + k - 512];
  W[i] = __half_as_ushort(__float2half_rn(v));
}

__global__ __launch_bounds__(NT, 2) void forecast_kernel(Args a) {
  extern __shared__ char smem[];
  char* HC = smem;                           // [32][2048B] fp16 hcat, XOR-swizzled
  float* TT = (float*)(smem + ROWS * HROW);  // [8 waves][2 tiles][16][18]
  float* p_lds = TT + 8 * 576;               // [64]
  float* x_lds = p_lds + 64;                 // [32][9]
  float* WxL = x_lds + 288;                  // [2 sets][64 rows][9]
  float* bL = WxL + 1152;                    // [4 sets][4 gates][16 units]
  float* pWb = bL + 256;                     // [0..15] pW, [16..23] pb, [24..25] fcb

  const int tid = threadIdx.x;
  const int g = blockIdx.x >> 5;        // batch group 0..7
  const int s = blockIdx.x & 31;        // unit slice (s%8 = XCD -> L2-resident weights)
  const int lane = tid & 63, wid = tid >> 6;
  const int bb = lane & 15;             // batch row (A) / gate col (D)
  const int lq = lane >> 4;
  const int isL0 = (wid < 4);
  const int w4 = isL0 ? wid : wid - 4;
  const int uu = lane >> 4;
  const int unitL = w4 * 4 + uu;        // unit within slice
  unsigned* cnt = a.cnt + g * 32;
  unsigned bar = 0;
  float* TTw = TT + wid * 576;

  const int nkbE = isL0 ? 16 : 32;
  const unsigned short* wE = a.W + (isL0 ? WE0 : WE1) + (size_t)(s * 4 + w4) * nkbE * 512 + lane * 8;
  const unsigned short* wD = a.W + (isL0 ? WD0 : WD1) + (size_t)(s * 4 + w4) * nkbE * 512 + lane * 8;

  for (int e = tid; e < 1152; e += NT) {
    int set = e / 576, e2 = e % 576, row = e2 / 9, k = e2 % 9;
    const float* sw = set ? a.dWih0 : a.eWih0;
    WxL[e] = (k < 8) ? sw[(size_t)((row >> 4) * 512 + 16 * s + (row & 15)) * 8 + k] : 0.f;
  }
  if (tid < 256) {
    int bs = tid >> 6, q = (tid >> 4) & 3, u2 = tid & 15;
    const float* sp = bs == 0 ? a.eb0 : bs == 1 ? a.eb1 : bs == 2 ? a.db0 : a.db1;
    bL[tid] = sp[q * 512 + 16 * s + u2];
  }
  if (tid < 16) pWb[tid] = a.pW[tid];
  else if (tid < 24) pWb[tid] = a.pb[tid - 16];
  else if (tid < 26) pWb[tid] = a.fcb[tid - 24];
  __syncthreads();

  float cA = 0.f, cB = 0.f;            // cell state rows bb / bb+16 (layer by wave)
  const int srow = tid >> 4, seg = tid & 15;
  const int wswz = (srow & 7) << 4;
  const int aswz = (bb & 7) << 4;      // same for row bb and bb+16
  const int rowG0 = 32 * g + bb, rowG1 = rowG0 + 16;

  // ---------- staging helpers ----------
  auto stage2 = [&](const unsigned short* b0, const unsigned short* b1) {
    const unsigned short* p0 = b0 + (size_t)(32 * g + srow) * 512 + seg * 8;
    const unsigned short* p1 = b1 + (size_t)(32 * g + srow) * 512 + seg * 8;
    uint4 q0, q1, q2, q3, q4, q5, q6, q7;
    ld16_cg(q0, p0); ld16_cg(q1, p0 + 128); ld16_cg(q2, p0 + 256); ld16_cg(q3, p0 + 384);
    ld16_cg(q4, p1); ld16_cg(q5, p1 + 128); ld16_cg(q6, p1 + 256); ld16_cg(q7, p1 + 384);
    asm volatile("s_waitcnt vmcnt(0)" ::: "memory");
    __builtin_amdgcn_sched_barrier(0);
    char* d = HC + srow * HROW + ((seg * 16) ^ wswz);
    *(uint4*)(d) = q0; *(uint4*)(d + 256) = q1; *(uint4*)(d + 512) = q2; *(uint4*)(d + 768) = q3;
    *(uint4*)(d + 1024) = q4; *(uint4*)(d + 1280) = q5; *(uint4*)(d + 1536) = q6; *(uint4*)(d + 1792) = q7;
  };
  auto stage1 = [&](const unsigned short* b0, int plane) {
    const unsigned short* p0 = b0 + (size_t)(32 * g + srow) * 512 + seg * 8;
    uint4 q0, q1, q2, q3;
    ld16_cg(q0, p0); ld16_cg(q1, p0 + 128); ld16_cg(q2, p0 + 256); ld16_cg(q3, p0 + 384);
    asm volatile("s_waitcnt vmcnt(0)" ::: "memory");
    __builtin_amdgcn_sched_barrier(0);
    char* d = HC + srow * HROW + plane + ((seg * 16) ^ wswz);
    *(uint4*)(d) = q0; *(uint4*)(d + 256) = q1; *(uint4*)(d + 512) = q2; *(uint4*)(d + 768) = q3;
  };
  auto mfma_dual = [&](const unsigned short* wp, int nkb, f32x4& acc0, f32x4& acc1) {
    const char* a0 = HC + bb * HROW;
    const char* a1 = HC + (16 + bb) * HROW;
    for (int kb = 0; kb < nkb; ++kb) {
      f16x8 bf = *(const f16x8*)(wp + (size_t)kb * 512);
      int off = (lq * 16 + kb * 64) ^ aswz;
      acc0 = mfma16(*(const f16x8*)(a0 + off), bf, acc0);
      acc1 = mfma16(*(const f16x8*)(a1 + off), bf, acc1);
    }
  };
  auto fcwave = [&](int t, bool writeOut) {   // waves 4,5: pred + x for 16 rows
    const int rowOff = (wid - 4) * 16;
    const int pb_ = lane & 15, dd = (lane >> 4) & 1, hf = lane >> 5;
    const int rloc = rowOff + pb_;
    const char* hp = HC + rloc * HROW;
    const int fswz = (pb_ & 7) << 4;
    const float* wr = a.fcW + dd * 512 + hf * 256;
    float r = 0.f;
    #pragma unroll 8
    for (int j = 0; j < 32; ++j) {
      f16x8 v = *(const f16x8*)(hp + ((1024 + hf * 512 + j * 16) ^ fswz));
      float4 w0 = *(const float4*)(wr + j * 8);
      float4 w1 = *(const float4*)(wr + j * 8 + 4);
      r = fmaf((float)v[0], w0.x, r); r = fmaf((float)v[1], w0.y, r);
      r = fmaf((float)v[2], w0.z, r); r = fmaf((float)v[3], w0.w, r);
      r = fmaf((float)v[4], w1.x, r); r = fmaf((float)v[5], w1.y, r);
      r = fmaf((float)v[6], w1.z, r); r = fmaf((float)v[7], w1.w, r);
    }
    r += __shfl_xor(r, 32);
    if (lane < 32) {
      float pred = r + pWb[24 + dd];
      if (t == 0) pred = a.src[(size_t)(32 * g + rloc) * (T_IN * F) + 335 * F + dd * 2];
      p_lds[rloc * 2 + dd] = pred;
      if (writeOut && s == 0 && t > 0)
        a.out[(size_t)(32 * g + rloc) * (T_OUT * D_OUT) + (size_t)(t - 1) * D_OUT + dd] = pred;
    }
    const int bx = rowOff + (lane >> 2), j0 = (lane & 3) * 2;
    float pr0 = p_lds[bx * 2], pr1 = p_lds[bx * 2 + 1];
    x_lds[bx * 9 + j0]     = pWb[16 + j0]     + pr0 * pWb[j0 * 2]       + pr1 * pWb[j0 * 2 + 1];
    x_lds[bx * 9 + j0 + 1] = pWb[16 + j0 + 1] + pr0 * pWb[(j0 + 1) * 2] + pr1 * pWb[(j0 + 1) * 2 + 1];
  };

  // ================= encoder =================
  for (int t = 0; t <= T_IN; ++t) {
    const int buf = t & 1, nbuf = buf ^ 1;
    stage2(a.Hst + HO0 + (size_t)buf * HBUF, a.Hst + HO1 + (size_t)buf * HBUF);
    __syncthreads();
    const bool active = isL0 ? (t < T_IN) : (t >= 1);
    if (active) {
      f32x4 acc0 = {0.f,0.f,0.f,0.f}, acc1 = {0.f,0.f,0.f,0.f};
      mfma_dual(wE, nkbE, acc0, acc1);
      #pragma unroll
      for (int j = 0; j < 4; ++j) {
        TTw[bb * 18 + lq * 4 + j] = acc0[j];
        TTw[288 + bb * 18 + lq * 4 + j] = acc1[j];
      }
      const int bset = isL0 ? 0 : 64;
      unsigned short* hplane = (unsigned short*)(a.Hst + (isL0 ? HO0 : HO1)) + (size_t)nbuf * HBUF;
      #pragma unroll
      for (int mt = 0; mt < 2; ++mt) {
        float ac[4];
        #pragma unroll
        for (int q = 0; q < 4; ++q)
          ac[q] = TTw[mt * 288 + (4 * uu + q) * 18 + bb] + bL[bset + q * 16 + unitL];
        float& cc = mt ? cB : cA;
        const int rg = mt ? rowG1 : rowG0;
        if (isL0) {
          const float* xr = a.src + (size_t)rg * (T_IN * F) + t * F;
          float4 x0 = *(const float4*)xr, x1 = *(const float4*)(xr + 4);
          float xv[8] = {x0.x, x0.y, x0.z, x0.w, x1.x, x1.y, x1.z, x1.w};
          #pragma unroll
          for (int q = 0; q < 4; ++q)
            #pragma unroll
            for (int k = 0; k < 8; ++k)
              ac[q] = fmaf(xv[k], WxL[(q * 16 + unitL) * 9 + k], ac[q]);
        }
        cc = sigm(ac[1]) * cc + sigm(ac[0]) * tanh_f(ac[2]);
        float h = sigm(ac[3]) * tanh_f(cc);
        st2_cg((void*)(hplane + (size_t)rg * 512 + 16 * s + unitL),
               (unsigned)__half_as_ushort(__float2half_rn(h)));
      }
    }
    gbarw(cnt, bar, lane);
  }

  // ================= decoder =================
  for (int t = 0; t < T_OUT; ++t) {
    const int pA = t & 1;
    stage2(a.Hst + HO0 + (size_t)pA * HBUF, a.Hst + HO1 + (size_t)(pA ^ 1) * HBUF);
    __syncthreads();
    if (isL0) {  // D0 gate MFMAs
      f32x4 acc0 = {0.f,0.f,0.f,0.f}, acc1 = {0.f,0.f,0.f,0.f};
      mfma_dual(wD, 16, acc0, acc1);
      #pragma unroll
      for (int j = 0; j < 4; ++j) {
        TTw[bb * 18 + lq * 4 + j] = acc0[j];
        TTw[288 + bb * 18 + lq * 4 + j] = acc1[j];
      }
    } else if (wid == 4 || wid == 5) {
      fcwave(t, true);
    }
    __syncthreads();
    if (isL0) {  // c0 update with x
      unsigned short* hplane = (unsigned short*)a.Hst + HO0 + (size_t)(pA ^ 1) * HBUF;
      #pragma unroll
      for (int mt = 0; mt < 2; ++mt) {
        float ac[4];
        #pragma unroll
        for (int q = 0; q < 4; ++q)
          ac[q] = TTw[mt * 288 + (4 * uu + q) * 18 + bb] + bL[128 + q * 16 + unitL];
        const int rloc = mt ? (16 + bb) : bb;
        #pragma unroll
        for (int q = 0; q < 4; ++q)
          #pragma unroll
          for (int k = 0; k < 8; ++k)
            ac[q] = fmaf(x_lds[rloc * 9 + k], WxL[576 + (q * 16 + unitL) * 9 + k], ac[q]);
        float& cc = mt ? cB : cA;
        cc = sigm(ac[1]) * cc + sigm(ac[0]) * tanh_f(ac[2]);
        float h = sigm(ac[3]) * tanh_f(cc);
        st2_cg((void*)(hplane + (size_t)(32 * g + rloc) * 512 + 16 * s + unitL),
               (unsigned)__half_as_ushort(__float2half_rn(h)));
      }
    }
    gbarw(cnt, bar, lane);
    stage1(a.Hst + HO0 + (size_t)(pA ^ 1) * HBUF, 0);
    __syncthreads();
    if (!isL0) {  // D1 gates + c1 update
      f32x4 acc0 = {0.f,0.f,0.f,0.f}, acc1 = {0.f,0.f,0.f,0.f};
      mfma_dual(wD, 32, acc0, acc1);
      #pragma unroll
      for (int j = 0; j < 4; ++j) {
        TTw[bb * 18 + lq * 4 + j] = acc0[j];
        TTw[288 + bb * 18 + lq * 4 + j] = acc1[j];
      }
      unsigned short* hplane = (unsigned short*)a.Hst + HO1 + (size_t)pA * HBUF;
      #pragma unroll
      for (int mt = 0; mt < 2; ++mt) {
        float ac[4];
        #pragma unroll
        for (int q = 0; q < 4; ++q)
          ac[q] = TTw[mt * 288 + (4 * uu + q) * 18 + bb] + bL[192 + q * 16 + unitL];
        float& cc = mt ? cB : cA;
        cc = sigm(ac[1]) * cc + sigm(ac[0]) * tanh_f(ac[2]);
        float h = sigm(ac[3]) * tanh_f(cc);
        const int rloc = mt ? (16 + bb) : bb;
        st2_cg((void*)(hplane + (size_t)(32 * g + rloc) * 512 + 16 * s + unitL),
               (unsigned)__half_as_ushort(__float2half_rn(h)));
      }
    }
    gbarw(cnt, bar, lane);
  }

  // ================= epilogue: pred(95) =================
  stage1(a.Hst + HO1 + (size_t)1 * HBUF, 1024);
  __syncthreads();
  if ((wid == 4 || wid == 5) && s == 0) {
    const int rowOff = (wid - 4) * 16;
    const int pb_ = lane & 15, dd = (lane >> 4) & 1, hf = lane >> 5;
    const char* hp = HC + (rowOff + pb_) * HROW;
    const int fswz = (pb_ & 7) << 4;
    const float* wr = a.fcW + dd * 512 + hf * 256;
    float r = 0.f;
    #pragma unroll 8
    for (int j = 0; j < 32; ++j) {
      f16x8 v = *(const f16x8*)(hp + ((1024 + hf * 512 + j * 16) ^ fswz));
      float4 w0 = *(const float4*)(wr + j * 8);
      float4 w1 = *(const float4*)(wr + j * 8 + 4);
      r = fmaf((float)v[0], w0.x, r); r = fmaf((float)v[1], w0.y, r);
      r = fmaf((float)v[2], w0.z, r); r = fmaf((float)v[3], w0.w, r);
      r = fmaf((float)v[4], w1.x, r); r = fmaf((float)v[5], w1.y, r);
      r = fmaf((float)v[6], w1.z, r); r = fmaf((float)v[7], w1.w, r);
    }
    r += __shfl_xor(r, 32);
    if (lane < 32)
      a.out[(size_t)(32 * g + rowOff + pb_) * (T_OUT * D_OUT) + (size_t)95 * D_OUT + dd] = r + pWb[24 + dd];
  }
}

extern "C" void kernel_launch(void* const* d_in, const int* in_sizes, int n_in,
                              void* d_out, int out_size, void* d_ws, size_t ws_size,
                              hipStream_t stream) {
  (void)in_sizes; (void)n_in; (void)out_size; (void)ws_size;
  const float* src   = (const float*)d_in[0];
  const float* eWih0 = (const float*)d_in[1];
  const float* eWhh0 = (const float*)d_in[2];
  const float* eb0   = (const float*)d_in[3];
  const float* eWih1 = (const float*)d_in[4];
  const float* eWhh1 = (const float*)d_in[5];
  const float* eb1   = (const float*)d_in[6];
  const float* dWih0 = (const float*)d_in[7];
  const float* dWhh0 = (const float*)d_in[8];
  const float* db0   = (const float*)d_in[9];
  const float* dWih1 = (const float*)d_in[10];
  const float* dWhh1 = (const float*)d_in[11];
  const float* db1   = (const float*)d_in[12];
  const float* fcW   = (const float*)d_in[13];
  const float* fcb   = (const float*)d_in[14];
  const float* pW    = (const float*)d_in[15];
  const float* pb    = (const float*)d_in[16];

  unsigned char* ws = (unsigned char*)d_ws;
  unsigned* cnt = (unsigned*)ws;                       // 4 KB
  unsigned short* W = (unsigned short*)(ws + 4096);    // 12.6 MB fp16 tiled weights
  unsigned short* Hst = W + W_TOTAL;                   // 1 MB fp16 h-state

  (void)hipMemsetAsync(d_ws, 0, 4096, stream);
  (void)hipMemsetAsync((void*)Hst, 0, (size_t)4 * HBUF * sizeof(unsigned short), stream);

  hipLaunchKernelGGL(conv_kernel, dim3(W_TOTAL / 256), dim3(256), 0, stream,
                     eWhh0, eWih1, eWhh1, dWhh0, dWih1, dWhh1, W);

  Args a;
  a.src = src; a.eWih0 = eWih0; a.eb0 = eb0; a.eb1 = eb1;
  a.dWih0 = dWih0; a.db0 = db0; a.db1 = db1;
  a.fcW = fcW; a.fcb = fcb; a.pW = pW; a.pb = pb;
  a.W = W; a.Hst = Hst; a.out = (float*)d_out; a.cnt = cnt;

  // LDS: 65536 (HC) + (4608 + 64 + 288 + 1152 + 256 + 32)*4 = 91136 B -> 1 block/CU
  const size_t smem_bytes = (size_t)ROWS * HROW + (4608 + 64 + 288 + 1152 + 256 + 32) * sizeof(float);
  hipLaunchKernelGGL(forecast_kernel, dim3(NGRP * WPG), dim3(NT), smem_bytes, stream, a);
}